// Round 6
// baseline (299.170 us; speedup 1.0000x reference)
//
#include <hip/hip_runtime.h>
#include <hip/hip_cooperative_groups.h>
namespace cg = cooperative_groups;

#define B_    32
#define CIN_  128
#define H_    64
#define W_    64
#define COUT_ 128
#define NK_   4
#define HID_  32
#define TEMP_ 34.0f

typedef short bf16x8 __attribute__((ext_vector_type(8)));
typedef float f32x16 __attribute__((ext_vector_type(16)));

__device__ __forceinline__ short f2bf(float f) {
    union { float f; unsigned u; } c; c.f = f;
    unsigned r = (c.u + 0x7FFFu + ((c.u >> 16) & 1u)) >> 16;
    return (short)r;
}

#define RBY 8448            // bytes per LDS row (66 slots * 128 B)
#define RSH 4224            // shorts per LDS row

// ================= fused cooperative kernel: ctx -> att+aggw -> conv =========
// 512 blocks x 256 thr = exactly 2 blocks/CU (LDS 2x50688<=160K, regs<=256 via
// launch_bounds) -> cooperative co-residency guaranteed. Two grid.sync()s
// replace two kernel boundaries. Phase 3 is the round-5-verified conv ring.
__global__ __launch_bounds__(256, 2) void k_fused(
        const float* __restrict__ x, const float* __restrict__ fc1w,
        const float* __restrict__ fc2w, const float* __restrict__ fc2b,
        const float* __restrict__ weight, const float* __restrict__ bias,
        float* __restrict__ out, float* __restrict__ ctx,
        short* __restrict__ aggwt, float* __restrict__ aggb) {
    __shared__ union {
        short xt[6 * RSH];                      // 50688 B (conv phase)
        struct {                                // 38032 B (phase 2)
            float hidp[8][32];
            float shid[32];
            float satt[NK_];
            float sbuf[9216];                   // 8 co x 128 ci x 9 r
        } p2;
    } sm;
    const int tid = threadIdx.x;
    const int blk = blockIdx.x;

    // ---------- phase 1: ctx[row] = mean(x[row]) ; row = (b,ci) ----------
    {
        const int row = blk * 8 + (tid >> 5);   // 512*8 = 4096 rows
        const int l32 = tid & 31;
        const float* p = x + (size_t)row * (H_ * W_);
        float s = 0.f;
#pragma unroll
        for (int k = 0; k < 32; ++k) {
            float4 v = *(const float4*)(p + l32 * 4 + k * 128);
            s += v.x + v.y + v.z + v.w;
        }
#pragma unroll
        for (int off = 16; off > 0; off >>= 1) s += __shfl_down(s, off, 32);
        if (l32 == 0) ctx[row] = s * (1.0f / (H_ * W_));
    }
    cg::this_grid().sync();

    // ---------- phase 2: attention + aggregate 8 co per block ----------
    {
        const int b2 = blk >> 4;                // 16 blocks per sample
        const int co0 = (blk & 15) * 8;
        {
            const int hh = tid & 31, part = tid >> 5;
            const float* c  = ctx + b2 * CIN_ + part * 16;
            const float* f1 = fc1w + hh * CIN_ + part * 16;
            float s = 0.f;
#pragma unroll
            for (int j = 0; j < 16; ++j) s += c[j] * f1[j];
            sm.p2.hidp[part][hh] = s;
        }
        __syncthreads();
        if (tid < 32) {
            float s = 0.f;
#pragma unroll
            for (int p = 0; p < 8; ++p) s += sm.p2.hidp[p][tid];
            sm.p2.shid[tid] = fmaxf(s, 0.f);
        }
        __syncthreads();
        if (tid == 0) {
            float lg[NK_]; float mx = -1e30f;
#pragma unroll
            for (int k = 0; k < NK_; ++k) {
                float s = fc2b[k];
                for (int hh = 0; hh < HID_; ++hh) s += sm.p2.shid[hh] * fc2w[k * HID_ + hh];
                lg[k] = s / TEMP_; mx = fmaxf(mx, lg[k]);
            }
            float den = 0.f;
#pragma unroll
            for (int k = 0; k < NK_; ++k) { lg[k] = expf(lg[k] - mx); den += lg[k]; }
            const float rd = 1.0f / den;
#pragma unroll
            for (int k = 0; k < NK_; ++k) sm.p2.satt[k] = lg[k] * rd;
        }
        __syncthreads();
        const float a0 = sm.p2.satt[0], a1 = sm.p2.satt[1],
                    a2 = sm.p2.satt[2], a3 = sm.p2.satt[3];

        if (tid < 8) {
            const int co = co0 + tid;
            aggb[b2 * COUT_ + co] = a0 * bias[co] + a1 * bias[COUT_ + co]
                                  + a2 * bias[2 * COUT_ + co] + a3 * bias[3 * COUT_ + co];
        }

        // coalesced aggregate: 2304 float4 (= 8co x 128ci x 9r) per stream
        const size_t kstride = (size_t)COUT_ * CIN_ * 9;
        const float* W0 = weight + (size_t)co0 * (CIN_ * 9);
#pragma unroll
        for (int jj = 0; jj < 9; ++jj) {
            const int i4 = jj * 256 + tid;
            const float4 w0 = *(const float4*)(W0 + i4 * 4);
            const float4 w1 = *(const float4*)(W0 + kstride + i4 * 4);
            const float4 w2 = *(const float4*)(W0 + 2 * kstride + i4 * 4);
            const float4 w3 = *(const float4*)(W0 + 3 * kstride + i4 * 4);
            float4 r;
            r.x = a0 * w0.x + a1 * w1.x + a2 * w2.x + a3 * w3.x;
            r.y = a0 * w0.y + a1 * w1.y + a2 * w2.y + a3 * w3.y;
            r.z = a0 * w0.z + a1 * w1.z + a2 * w2.z + a3 * w3.z;
            r.w = a0 * w0.w + a1 * w1.w + a2 * w2.w + a3 * w3.w;
            *(float4*)(&sm.p2.sbuf[i4 * 4]) = r;
        }
        __syncthreads();
        // transpose-write to fragment-major aggwt: 1152 groups (coL, r, oc)
#pragma unroll
        for (int jj = 0; jj < 5; ++jj) {
            const int g = jj * 256 + tid;
            if (g < 1152) {
                const int coL = g / 144;
                const int gg = g - coL * 144;
                const int r  = gg >> 4;
                const int oc = gg & 15;
                const int co = co0 + coL;
                bf16x8 v;
#pragma unroll
                for (int e = 0; e < 8; ++e)
                    v[e] = f2bf(sm.p2.sbuf[(coL * 128 + oc * 8 + e) * 9 + r]);
                short* dst = aggwt
                    + ((size_t)(((b2 * 4 + (co >> 5)) * 9 + r) * 8 + (oc >> 1)) * 512)
                    + ((co & 31) * 2 + (oc & 1)) * 8;
                *(bf16x8*)dst = v;
            }
        }
    }
    cg::this_grid().sync();

    // ---------- phase 3: conv (round-5 kc-ring, verbatim) ----------
    const int b = blk & 31;
    const int h0 = (blk >> 5) * 4;
    const int lane = tid & 63;
    const int wv = tid >> 6;
    const int l31 = lane & 31;
    const int lane5 = lane >> 5;

    // zero halo slots (slot 0 and slot 65 of each of 6 rows)
    if (tid < 96) {
        const int row = tid >> 4;
        const int q = tid & 15;
        const int cl = (q < 8) ? q : (512 + q);
        *(int4*)(&sm.xt[row * RSH + cl * 8]) = make_int4(0, 0, 0, 0);
    }

    f32x16 acc[8];
#pragma unroll
    for (int t = 0; t < 8; ++t)
#pragma unroll
        for (int k = 0; k < 16; ++k) acc[t][k] = 0.f;

    const short* Ap = aggwt + (size_t)(b * 4 + wv) * (9 * 8 * 512)
                            + (size_t)(l31 * 2 + lane5) * 8;

    // prologue: stage kc=0..3 (ci octets 0..7), 12 tasks/wave
#pragma unroll
    for (int k = 0; k < 12; ++k) {
        const int task = k * 4 + wv;          // wave-uniform
        const int row = task >> 3;
        const int g = task & 7;
        const int in_h = h0 - 1 + row;
        bf16x8 v = (bf16x8){0, 0, 0, 0, 0, 0, 0, 0};
        if (in_h >= 0 && in_h < H_) {
            const float* gp = x + (((size_t)b * CIN_ + g * 8) * H_ + in_h) * W_ + lane;
            float f[8];
#pragma unroll
            for (int j = 0; j < 8; ++j) f[j] = gp[j * (H_ * W_)];
#pragma unroll
            for (int j = 0; j < 8; ++j) v[j] = f2bf(f[j]);
        }
        *(bf16x8*)(&sm.xt[row * RSH + ((lane + 1) * 8 + ((g + lane) & 7)) * 8]) = v;
    }
    __syncthreads();

    // main ring loop over kc = 0..7 (16 ci each)
#pragma unroll
    for (int kc = 0; kc < 8; ++kc) {
        float sf[3][8];
        if (kc < 4) {
#pragma unroll
            for (int k = 0; k < 3; ++k) {
                const int task = k * 4 + wv;
                const int row = task >> 1;
                const int j = task & 1;
                const int in_h = h0 - 1 + row;
                if (in_h >= 0 && in_h < H_) {
                    const float* gp = x + (((size_t)b * CIN_ + 64 + (2 * kc + j) * 8) * H_
                                           + in_h) * W_ + lane;
#pragma unroll
                    for (int jj = 0; jj < 8; ++jj) sf[k][jj] = gp[jj * (H_ * W_)];
                }
            }
        }
        bf16x8 av[9];
#pragma unroll
        for (int r = 0; r < 9; ++r)
            av[r] = *(const bf16x8*)(Ap + ((size_t)(r * 8 + kc)) * 512);
        const int kcl = kc & 3;
        __builtin_amdgcn_s_setprio(1);
#pragma unroll
        for (int ir = 0; ir < 6; ++ir) {
            bf16x8 bv[2][3];
#pragma unroll
            for (int i = 0; i < 2; ++i)
#pragma unroll
                for (int kw = 0; kw < 3; ++kw) {
                    const int s = i * 32 + l31 + kw;
                    const int off = 16 * ((2 * kcl + lane5 + s - 1) & 7);
                    bv[i][kw] = *(const bf16x8*)((const char*)sm.xt + ir * RBY + s * 128 + off);
                }
#pragma unroll
            for (int orr = 0; orr < 4; ++orr) {
                if (orr <= ir && ir <= orr + 2) {
                    const int kh = ir - orr;
#pragma unroll
                    for (int i = 0; i < 2; ++i)
#pragma unroll
                        for (int kw = 0; kw < 3; ++kw)
                            acc[orr * 2 + i] = __builtin_amdgcn_mfma_f32_32x32x16_bf16(
                                av[kh * 3 + kw], bv[i][kw], acc[orr * 2 + i], 0, 0, 0);
                }
            }
        }
        __builtin_amdgcn_s_setprio(0);
        if (kc <= 4) __syncthreads();
        if (kc < 4) {
#pragma unroll
            for (int k = 0; k < 3; ++k) {
                const int task = k * 4 + wv;
                const int row = task >> 1;
                const int j = task & 1;
                const int in_h = h0 - 1 + row;
                const int g = 2 * kc + j;
                bf16x8 v = (bf16x8){0, 0, 0, 0, 0, 0, 0, 0};
                if (in_h >= 0 && in_h < H_) {
#pragma unroll
                    for (int jj = 0; jj < 8; ++jj) v[jj] = f2bf(sf[k][jj]);
                }
                *(bf16x8*)(&sm.xt[row * RSH + ((lane + 1) * 8 + ((g + lane) & 7)) * 8]) = v;
            }
        }
    }

    const float* ab = aggb + b * COUT_;
#pragma unroll
    for (int orr = 0; orr < 4; ++orr) {
#pragma unroll
        for (int i = 0; i < 2; ++i) {
            const int hh = h0 + orr;
            const int w = i * 32 + l31;
            float* op = out + ((size_t)b * COUT_ * H_ + hh) * W_ + w;
            const f32x16 a = acc[orr * 2 + i];
#pragma unroll
            for (int reg = 0; reg < 16; ++reg) {
                const int co = wv * 32 + (reg & 3) + 8 * (reg >> 2) + 4 * lane5;
                op[(size_t)co * (H_ * W_)] = a[reg] + ab[co];
            }
        }
    }
}

// ==================== fallback path: round-5 proven 3-kernel =================
__global__ __launch_bounds__(64) void k_context(const float* __restrict__ x,
                                                float* __restrict__ ctx) {
    const int bc = blockIdx.x;
    const float* p = x + (size_t)bc * (H_ * W_);
    const int lane = threadIdx.x;
    float s = 0.f;
    for (int i = lane * 4; i < H_ * W_; i += 64 * 4) {
        float4 v = *(const float4*)(p + i);
        s += v.x + v.y + v.z + v.w;
    }
    for (int off = 32; off > 0; off >>= 1) s += __shfl_down(s, off, 64);
    if (lane == 0) ctx[bc] = s * (1.0f / (H_ * W_));
}

__global__ __launch_bounds__(256) void k_aggw(const float* __restrict__ ctx,
        const float* __restrict__ fc1w, const float* __restrict__ fc2w,
        const float* __restrict__ fc2b, const float* __restrict__ bias,
        const float* __restrict__ weight, short* __restrict__ aggwt,
        float* __restrict__ aggb) {
    __shared__ float hidp[8][32];
    __shared__ float shid[32];
    __shared__ float satt[NK_];
    __shared__ float sbuf[2304];
    const int t = threadIdx.x;
    const int blk = blockIdx.x;
    const int b = blk >> 6;
    const int co0 = (blk & 63) * 2;
    {
        const int hh = t & 31, part = t >> 5;
        const float* c  = ctx + b * CIN_ + part * 16;
        const float* f1 = fc1w + hh * CIN_ + part * 16;
        float s = 0.f;
#pragma unroll
        for (int j = 0; j < 16; ++j) s += c[j] * f1[j];
        hidp[part][hh] = s;
    }
    __syncthreads();
    if (t < 32) {
        float s = 0.f;
#pragma unroll
        for (int p = 0; p < 8; ++p) s += hidp[p][t];
        shid[t] = fmaxf(s, 0.f);
    }
    __syncthreads();
    if (t == 0) {
        float lg[NK_]; float mx = -1e30f;
#pragma unroll
        for (int k = 0; k < NK_; ++k) {
            float s = fc2b[k];
            for (int hh = 0; hh < HID_; ++hh) s += shid[hh] * fc2w[k * HID_ + hh];
            lg[k] = s / TEMP_; mx = fmaxf(mx, lg[k]);
        }
        float den = 0.f;
#pragma unroll
        for (int k = 0; k < NK_; ++k) { lg[k] = expf(lg[k] - mx); den += lg[k]; }
        const float rd = 1.0f / den;
#pragma unroll
        for (int k = 0; k < NK_; ++k) satt[k] = lg[k] * rd;
    }
    __syncthreads();
    const float a0 = satt[0], a1 = satt[1], a2 = satt[2], a3 = satt[3];
    if ((t & 127) == 0) {
        const int co = co0 + (t >> 7);
        aggb[b * COUT_ + co] = a0 * bias[co] + a1 * bias[COUT_ + co]
                             + a2 * bias[2 * COUT_ + co] + a3 * bias[3 * COUT_ + co];
    }
    const size_t kstride = (size_t)COUT_ * CIN_ * 9;
    const float* W0 = weight + (size_t)co0 * (CIN_ * 9);
#pragma unroll
    for (int jj = 0; jj < 3; ++jj) {
        const int i4 = jj * 256 + t;
        if (i4 < 576) {
            const float4 w0 = *(const float4*)(W0 + i4 * 4);
            const float4 w1 = *(const float4*)(W0 + kstride + i4 * 4);
            const float4 w2 = *(const float4*)(W0 + 2 * kstride + i4 * 4);
            const float4 w3 = *(const float4*)(W0 + 3 * kstride + i4 * 4);
            float4 r;
            r.x = a0 * w0.x + a1 * w1.x + a2 * w2.x + a3 * w3.x;
            r.y = a0 * w0.y + a1 * w1.y + a2 * w2.y + a3 * w3.y;
            r.z = a0 * w0.z + a1 * w1.z + a2 * w2.z + a3 * w3.z;
            r.w = a0 * w0.w + a1 * w1.w + a2 * w2.w + a3 * w3.w;
            *(float4*)(&sbuf[i4 * 4]) = r;
        }
    }
    __syncthreads();
#pragma unroll
    for (int jj = 0; jj < 2; ++jj) {
        const int g = jj * 256 + t;
        if (g < 288) {
            const int coL = (g >= 144) ? 1 : 0;
            const int gg = g - coL * 144;
            const int r  = gg >> 4;
            const int oc = gg & 15;
            const int co = co0 + coL;
            bf16x8 v;
#pragma unroll
            for (int e = 0; e < 8; ++e)
                v[e] = f2bf(sbuf[(coL * 128 + oc * 8 + e) * 9 + r]);
            short* dst = aggwt
                + ((size_t)(((b * 4 + (co >> 5)) * 9 + r) * 8 + (oc >> 1)) * 512)
                + ((co & 31) * 2 + (oc & 1)) * 8;
            *(bf16x8*)dst = v;
        }
    }
}

__global__ __launch_bounds__(256, 2) void k_conv(const float* __restrict__ x,
        const short* __restrict__ aggwt, const float* __restrict__ aggb,
        float* __restrict__ out) {
    __shared__ short xt[6 * RSH];
    const int tid = threadIdx.x;
    const int blk = blockIdx.x;
    const int b = blk & 31;
    const int h0 = (blk >> 5) * 4;
    const int lane = tid & 63;
    const int wv = tid >> 6;
    const int l31 = lane & 31;
    const int lane5 = lane >> 5;
    if (tid < 96) {
        const int row = tid >> 4;
        const int q = tid & 15;
        const int cl = (q < 8) ? q : (512 + q);
        *(int4*)(&xt[row * RSH + cl * 8]) = make_int4(0, 0, 0, 0);
    }
    f32x16 acc[8];
#pragma unroll
    for (int t = 0; t < 8; ++t)
#pragma unroll
        for (int k = 0; k < 16; ++k) acc[t][k] = 0.f;
    const short* Ap = aggwt + (size_t)(b * 4 + wv) * (9 * 8 * 512)
                            + (size_t)(l31 * 2 + lane5) * 8;
#pragma unroll
    for (int k = 0; k < 12; ++k) {
        const int task = k * 4 + wv;
        const int row = task >> 3;
        const int g = task & 7;
        const int in_h = h0 - 1 + row;
        bf16x8 v = (bf16x8){0, 0, 0, 0, 0, 0, 0, 0};
        if (in_h >= 0 && in_h < H_) {
            const float* gp = x + (((size_t)b * CIN_ + g * 8) * H_ + in_h) * W_ + lane;
            float f[8];
#pragma unroll
            for (int j = 0; j < 8; ++j) f[j] = gp[j * (H_ * W_)];
#pragma unroll
            for (int j = 0; j < 8; ++j) v[j] = f2bf(f[j]);
        }
        *(bf16x8*)(&xt[row * RSH + ((lane + 1) * 8 + ((g + lane) & 7)) * 8]) = v;
    }
    __syncthreads();
#pragma unroll
    for (int kc = 0; kc < 8; ++kc) {
        float sf[3][8];
        if (kc < 4) {
#pragma unroll
            for (int k = 0; k < 3; ++k) {
                const int task = k * 4 + wv;
                const int row = task >> 1;
                const int j = task & 1;
                const int in_h = h0 - 1 + row;
                if (in_h >= 0 && in_h < H_) {
                    const float* gp = x + (((size_t)b * CIN_ + 64 + (2 * kc + j) * 8) * H_
                                           + in_h) * W_ + lane;
#pragma unroll
                    for (int jj = 0; jj < 8; ++jj) sf[k][jj] = gp[jj * (H_ * W_)];
                }
            }
        }
        bf16x8 av[9];
#pragma unroll
        for (int r = 0; r < 9; ++r)
            av[r] = *(const bf16x8*)(Ap + ((size_t)(r * 8 + kc)) * 512);
        const int kcl = kc & 3;
        __builtin_amdgcn_s_setprio(1);
#pragma unroll
        for (int ir = 0; ir < 6; ++ir) {
            bf16x8 bv[2][3];
#pragma unroll
            for (int i = 0; i < 2; ++i)
#pragma unroll
                for (int kw = 0; kw < 3; ++kw) {
                    const int s = i * 32 + l31 + kw;
                    const int off = 16 * ((2 * kcl + lane5 + s - 1) & 7);
                    bv[i][kw] = *(const bf16x8*)((const char*)xt + ir * RBY + s * 128 + off);
                }
#pragma unroll
            for (int orr = 0; orr < 4; ++orr) {
                if (orr <= ir && ir <= orr + 2) {
                    const int kh = ir - orr;
#pragma unroll
                    for (int i = 0; i < 2; ++i)
#pragma unroll
                        for (int kw = 0; kw < 3; ++kw)
                            acc[orr * 2 + i] = __builtin_amdgcn_mfma_f32_32x32x16_bf16(
                                av[kh * 3 + kw], bv[i][kw], acc[orr * 2 + i], 0, 0, 0);
                }
            }
        }
        __builtin_amdgcn_s_setprio(0);
        if (kc <= 4) __syncthreads();
        if (kc < 4) {
#pragma unroll
            for (int k = 0; k < 3; ++k) {
                const int task = k * 4 + wv;
                const int row = task >> 1;
                const int j = task & 1;
                const int in_h = h0 - 1 + row;
                const int g = 2 * kc + j;
                bf16x8 v = (bf16x8){0, 0, 0, 0, 0, 0, 0, 0};
                if (in_h >= 0 && in_h < H_) {
#pragma unroll
                    for (int jj = 0; jj < 8; ++jj) v[jj] = f2bf(sf[k][jj]);
                }
                *(bf16x8*)(&xt[row * RSH + ((lane + 1) * 8 + ((g + lane) & 7)) * 8]) = v;
            }
        }
    }
    const float* ab = aggb + b * COUT_;
#pragma unroll
    for (int orr = 0; orr < 4; ++orr) {
#pragma unroll
        for (int i = 0; i < 2; ++i) {
            const int hh = h0 + orr;
            const int w = i * 32 + l31;
            float* op = out + ((size_t)b * COUT_ * H_ + hh) * W_ + w;
            const f32x16 a = acc[orr * 2 + i];
#pragma unroll
            for (int reg = 0; reg < 16; ++reg) {
                const int co = wv * 32 + (reg & 3) + 8 * (reg >> 2) + 4 * lane5;
                op[(size_t)co * (H_ * W_)] = a[reg] + ab[co];
            }
        }
    }
}

extern "C" void kernel_launch(void* const* d_in, const int* in_sizes, int n_in,
                              void* d_out, int out_size, void* d_ws, size_t ws_size,
                              hipStream_t stream) {
    const float* x    = (const float*)d_in[0];
    const float* fc1w = (const float*)d_in[1];
    const float* fc2w = (const float*)d_in[2];
    const float* fc2b = (const float*)d_in[3];
    const float* wgt  = (const float*)d_in[4];
    const float* bias = (const float*)d_in[5];
    float* out = (float*)d_out;

    char* ws = (char*)d_ws;
    float* ctx   = (float*)(ws + 0);            // 16 KB
    float* aggb  = (float*)(ws + 16384);        // 16 KB
    short* aggwt = (short*)(ws + 65536);        // 9,437,184 B

    void* kargs[] = {(void*)&x, (void*)&fc1w, (void*)&fc2w, (void*)&fc2b,
                     (void*)&wgt, (void*)&bias, (void*)&out,
                     (void*)&ctx, (void*)&aggwt, (void*)&aggb};
    hipError_t e = hipLaunchCooperativeKernel((const void*)k_fused,
                                              dim3(512), dim3(256), kargs, 0, stream);
    if (e != hipSuccess) {
        // proven round-5 3-kernel path
        k_context<<<dim3(B_ * CIN_), dim3(64), 0, stream>>>(x, ctx);
        k_aggw<<<dim3(B_ * (COUT_ / 2)), dim3(256), 0, stream>>>(
            ctx, fc1w, fc2w, fc2b, bias, wgt, aggwt, aggb);
        k_conv<<<dim3(B_ * (H_ / 4)), dim3(256), 0, stream>>>(x, aggwt, aggb, out);
    }
}

// Round 7
// 161.963 us; speedup vs baseline: 1.8472x; 1.8472x over previous
//
#include <hip/hip_runtime.h>

#define B_    32
#define CIN_  128
#define H_    64
#define W_    64
#define COUT_ 128
#define NK_   4
#define HID_  32
#define TEMP_ 34.0f

typedef short bf16x8 __attribute__((ext_vector_type(8)));
typedef float f32x16 __attribute__((ext_vector_type(16)));

__device__ __forceinline__ short f2bf(float f) {
    union { float f; unsigned u; } c; c.f = f;
    unsigned r = (c.u + 0x7FFFu + ((c.u >> 16) & 1u)) >> 16;
    return (short)r;
}

// =========== k_context: ctx[row] = mean over HxW; 4 rows/block (4 waves) ====
__global__ __launch_bounds__(256) void k_context(const float* __restrict__ x,
                                                 float* __restrict__ ctx) {
    const int row = blockIdx.x * 4 + (threadIdx.x >> 6);
    const int lane = threadIdx.x & 63;
    const float* p = x + (size_t)row * (H_ * W_);
    float s = 0.f;
#pragma unroll
    for (int k = 0; k < 16; ++k) {
        float4 v = *(const float4*)(p + lane * 4 + k * 256);
        s += v.x + v.y + v.z + v.w;
    }
    for (int off = 32; off > 0; off >>= 1) s += __shfl_down(s, off, 64);
    if (lane == 0) ctx[row] = s * (1.0f / (H_ * W_));
}

// =========== k_aggw: fused attention + weight aggregation + agg bias =========
// aggwt layout (fragment-major): [b][wg=co>>5][r][kc=ci>>4][co&31][(ci>>3)&1]
// Round-7 fix: sbuf leading stride 9 -> 17 (prime). Old stride-9 transpose
// read had lane-to-lane stride 72 floats (72%32=8 -> 4 banks -> 16-way
// conflict, ~14M conflict-cycles measured in round-6 fused). Stride 17:
// bank = (8*oc + r + 17e) % 32 spans 16 banks -> 4-way (~free per m136).
__global__ __launch_bounds__(256) void k_aggw(const float* __restrict__ ctx,
        const float* __restrict__ fc1w, const float* __restrict__ fc2w,
        const float* __restrict__ fc2b, const float* __restrict__ bias,
        const float* __restrict__ weight, short* __restrict__ aggwt,
        float* __restrict__ aggb) {
    __shared__ float hidp[8][32];
    __shared__ float shid[32];
    __shared__ float satt[NK_];
    __shared__ float sbuf[2 * 128 * 17];  // [coL][ci] stride 17, r in 0..8
    const int t = threadIdx.x;
    const int blk = blockIdx.x;
    const int b = blk >> 6;               // 64 blocks per sample
    const int co0 = (blk & 63) * 2;
    // --- attention (tiny, redundant per block) ---
    {
        const int hh = t & 31, part = t >> 5;
        const float* c  = ctx + b * CIN_ + part * 16;
        const float* f1 = fc1w + hh * CIN_ + part * 16;
        float s = 0.f;
#pragma unroll
        for (int j = 0; j < 16; ++j) s += c[j] * f1[j];
        hidp[part][hh] = s;
    }
    __syncthreads();
    if (t < 32) {
        float s = 0.f;
#pragma unroll
        for (int p = 0; p < 8; ++p) s += hidp[p][t];
        shid[t] = fmaxf(s, 0.f);
    }
    __syncthreads();
    if (t == 0) {
        float lg[NK_]; float mx = -1e30f;
#pragma unroll
        for (int k = 0; k < NK_; ++k) {
            float s = fc2b[k];
            for (int hh = 0; hh < HID_; ++hh) s += shid[hh] * fc2w[k * HID_ + hh];
            lg[k] = s / TEMP_; mx = fmaxf(mx, lg[k]);
        }
        float den = 0.f;
#pragma unroll
        for (int k = 0; k < NK_; ++k) { lg[k] = expf(lg[k] - mx); den += lg[k]; }
        const float rd = 1.0f / den;
#pragma unroll
        for (int k = 0; k < NK_; ++k) satt[k] = lg[k] * rd;
    }
    __syncthreads();
    const float a0 = satt[0], a1 = satt[1], a2 = satt[2], a3 = satt[3];

    if ((t & 127) == 0) {
        const int co = co0 + (t >> 7);
        aggb[b * COUT_ + co] = a0 * bias[co] + a1 * bias[COUT_ + co]
                             + a2 * bias[2 * COUT_ + co] + a3 * bias[3 * COUT_ + co];
    }

    // --- coalesced aggregate: 576 float4 per k-stream; scalar swizzled write -
    const size_t kstride = (size_t)COUT_ * CIN_ * 9;
    const float* W0 = weight + (size_t)co0 * (CIN_ * 9);
#pragma unroll
    for (int jj = 0; jj < 3; ++jj) {
        const int i4 = jj * 256 + t;
        if (i4 < 576) {
            const float4 w0 = *(const float4*)(W0 + i4 * 4);
            const float4 w1 = *(const float4*)(W0 + kstride + i4 * 4);
            const float4 w2 = *(const float4*)(W0 + 2 * kstride + i4 * 4);
            const float4 w3 = *(const float4*)(W0 + 3 * kstride + i4 * 4);
            float r4[4];
            r4[0] = a0 * w0.x + a1 * w1.x + a2 * w2.x + a3 * w3.x;
            r4[1] = a0 * w0.y + a1 * w1.y + a2 * w2.y + a3 * w3.y;
            r4[2] = a0 * w0.z + a1 * w1.z + a2 * w2.z + a3 * w3.z;
            r4[3] = a0 * w0.w + a1 * w1.w + a2 * w2.w + a3 * w3.w;
#pragma unroll
            for (int j = 0; j < 4; ++j) {
                const unsigned f = (unsigned)(i4 * 4 + j);   // flat (coL,ci,r)
                const unsigned ci = f / 9u;                  // magic-div
                const unsigned rr = f - ci * 9u;
                sbuf[ci * 17 + rr] = r4[j];
            }
        }
    }
    __syncthreads();
    // --- transpose-read + store: group g = (coL, r, oc), 288 groups ---
#pragma unroll
    for (int jj = 0; jj < 2; ++jj) {
        const int g = jj * 256 + t;
        if (g < 288) {
            const int coL = (g >= 144) ? 1 : 0;
            const int gg = g - coL * 144;
            const int r  = gg >> 4;
            const int oc = gg & 15;
            const int co = co0 + coL;
            const float* src = &sbuf[(coL * 128 + oc * 8) * 17 + r];
            bf16x8 v;
#pragma unroll
            for (int e = 0; e < 8; ++e)
                v[e] = f2bf(src[e * 17]);
            short* dst = aggwt
                + ((size_t)(((b * 4 + (co >> 5)) * 9 + r) * 8 + (oc >> 1)) * 512)
                + ((co & 31) * 2 + (oc & 1)) * 8;
            *(bf16x8*)dst = v;
        }
    }
}

// =========== k_conv: kc-ring software pipeline (round-5 proven, verbatim) ====
#define RBY 8448            // bytes per LDS row (66 slots * 128 B)
#define RSH 4224            // shorts per LDS row
__global__ __launch_bounds__(256, 2) void k_conv(const float* __restrict__ x,
        const short* __restrict__ aggwt, const float* __restrict__ aggb,
        float* __restrict__ out) {
    __shared__ short xt[6 * RSH];
    const int tid = threadIdx.x;
    const int blk = blockIdx.x;
    const int b = blk & 31;                 // all 16 blocks of b on XCD b&7
    const int h0 = (blk >> 5) * 4;
    const int lane = tid & 63;
    const int wv = tid >> 6;
    const int l31 = lane & 31;
    const int lane5 = lane >> 5;

    // zero halo slots (slot 0 and slot 65 of each of 6 rows)
    if (tid < 96) {
        const int row = tid >> 4;
        const int q = tid & 15;
        const int cl = (q < 8) ? q : (512 + q);
        *(int4*)(&xt[row * RSH + cl * 8]) = make_int4(0, 0, 0, 0);
    }

    f32x16 acc[8];
#pragma unroll
    for (int t = 0; t < 8; ++t)
#pragma unroll
        for (int k = 0; k < 16; ++k) acc[t][k] = 0.f;

    const short* Ap = aggwt + (size_t)(b * 4 + wv) * (9 * 8 * 512)
                            + (size_t)(l31 * 2 + lane5) * 8;

    // prologue: stage kc=0..3 (ci octets 0..7), 12 tasks/wave
#pragma unroll
    for (int k = 0; k < 12; ++k) {
        const int task = k * 4 + wv;          // wave-uniform
        const int row = task >> 3;
        const int g = task & 7;
        const int in_h = h0 - 1 + row;
        bf16x8 v = (bf16x8){0, 0, 0, 0, 0, 0, 0, 0};
        if (in_h >= 0 && in_h < H_) {
            const float* gp = x + (((size_t)b * CIN_ + g * 8) * H_ + in_h) * W_ + lane;
            float f[8];
#pragma unroll
            for (int j = 0; j < 8; ++j) f[j] = gp[j * (H_ * W_)];
#pragma unroll
            for (int j = 0; j < 8; ++j) v[j] = f2bf(f[j]);
        }
        *(bf16x8*)(&xt[row * RSH + ((lane + 1) * 8 + ((g + lane) & 7)) * 8]) = v;
    }
    __syncthreads();

    // main ring loop over kc = 0..7 (16 ci each)
#pragma unroll
    for (int kc = 0; kc < 8; ++kc) {
        float sf[3][8];
        if (kc < 4) {
#pragma unroll
            for (int k = 0; k < 3; ++k) {
                const int task = k * 4 + wv;
                const int row = task >> 1;
                const int j = task & 1;
                const int in_h = h0 - 1 + row;
                if (in_h >= 0 && in_h < H_) {
                    const float* gp = x + (((size_t)b * CIN_ + 64 + (2 * kc + j) * 8) * H_
                                           + in_h) * W_ + lane;
#pragma unroll
                    for (int jj = 0; jj < 8; ++jj) sf[k][jj] = gp[jj * (H_ * W_)];
                }
            }
        }
        bf16x8 av[9];
#pragma unroll
        for (int r = 0; r < 9; ++r)
            av[r] = *(const bf16x8*)(Ap + ((size_t)(r * 8 + kc)) * 512);
        const int kcl = kc & 3;
        __builtin_amdgcn_s_setprio(1);
#pragma unroll
        for (int ir = 0; ir < 6; ++ir) {
            bf16x8 bv[2][3];
#pragma unroll
            for (int i = 0; i < 2; ++i)
#pragma unroll
                for (int kw = 0; kw < 3; ++kw) {
                    const int s = i * 32 + l31 + kw;
                    const int off = 16 * ((2 * kcl + lane5 + s - 1) & 7);
                    bv[i][kw] = *(const bf16x8*)((const char*)xt + ir * RBY + s * 128 + off);
                }
#pragma unroll
            for (int orr = 0; orr < 4; ++orr) {
                if (orr <= ir && ir <= orr + 2) {
                    const int kh = ir - orr;
#pragma unroll
                    for (int i = 0; i < 2; ++i)
#pragma unroll
                        for (int kw = 0; kw < 3; ++kw)
                            acc[orr * 2 + i] = __builtin_amdgcn_mfma_f32_32x32x16_bf16(
                                av[kh * 3 + kw], bv[i][kw], acc[orr * 2 + i], 0, 0, 0);
                }
            }
        }
        __builtin_amdgcn_s_setprio(0);
        if (kc <= 4) __syncthreads();
        if (kc < 4) {
#pragma unroll
            for (int k = 0; k < 3; ++k) {
                const int task = k * 4 + wv;
                const int row = task >> 1;
                const int j = task & 1;
                const int in_h = h0 - 1 + row;
                const int g = 2 * kc + j;
                bf16x8 v = (bf16x8){0, 0, 0, 0, 0, 0, 0, 0};
                if (in_h >= 0 && in_h < H_) {
#pragma unroll
                    for (int jj = 0; jj < 8; ++jj) v[jj] = f2bf(sf[k][jj]);
                }
                *(bf16x8*)(&xt[row * RSH + ((lane + 1) * 8 + ((g + lane) & 7)) * 8]) = v;
            }
        }
    }

    const float* ab = aggb + b * COUT_;
#pragma unroll
    for (int orr = 0; orr < 4; ++orr) {
#pragma unroll
        for (int i = 0; i < 2; ++i) {
            const int hh = h0 + orr;
            const int w = i * 32 + l31;
            float* op = out + ((size_t)b * COUT_ * H_ + hh) * W_ + w;
            const f32x16 a = acc[orr * 2 + i];
#pragma unroll
            for (int reg = 0; reg < 16; ++reg) {
                const int co = wv * 32 + (reg & 3) + 8 * (reg >> 2) + 4 * lane5;
                op[(size_t)co * (H_ * W_)] = a[reg] + ab[co];
            }
        }
    }
}

extern "C" void kernel_launch(void* const* d_in, const int* in_sizes, int n_in,
                              void* d_out, int out_size, void* d_ws, size_t ws_size,
                              hipStream_t stream) {
    const float* x    = (const float*)d_in[0];
    const float* fc1w = (const float*)d_in[1];
    const float* fc2w = (const float*)d_in[2];
    const float* fc2b = (const float*)d_in[3];
    const float* wgt  = (const float*)d_in[4];
    const float* bias = (const float*)d_in[5];
    float* out = (float*)d_out;

    char* ws = (char*)d_ws;
    float* ctx   = (float*)(ws + 0);            // 16 KB
    float* aggb  = (float*)(ws + 16384);        // 16 KB
    short* aggwt = (short*)(ws + 65536);        // 9,437,184 B

    k_context<<<dim3(B_ * CIN_ / 4), dim3(256), 0, stream>>>(x, ctx);
    k_aggw<<<dim3(B_ * (COUT_ / 2)), dim3(256), 0, stream>>>(
        ctx, fc1w, fc2w, fc2b, bias, wgt, aggwt, aggb);
    k_conv<<<dim3(B_ * (H_ / 4)), dim3(256), 0, stream>>>(x, aggwt, aggb, out);
}